// Round 1
// baseline (246.361 us; speedup 1.0000x reference)
//
#include <hip/hip_runtime.h>
#include <math.h>

// Problem constants (from reference setup_inputs): B=1024, N=200, E=128, fp32.
constexpr int Bc = 1024;
constexpr int Nc = 200;
constexpr int Ec = 128;

// One block per batch b. 256 threads = 8 half-waves of 32 lanes.
// Each half-wave processes one row n per pass: 32 lanes x float4 = 128 elems.
__global__ __launch_bounds__(256) void fused_dist_softmax(
    const float* __restrict__ q,      // (B,E)
    const float* __restrict__ q_p,    // (B,E)
    const float* __restrict__ m,      // (B,N,E)
    const float* __restrict__ m_c,    // (B,N,E)
    const float* __restrict__ A1,     // (E,1) -> flat E
    const float* __restrict__ A2,     // (E,1) -> flat E
    const float* __restrict__ biases, // (B,N)
    const float* __restrict__ mask,   // (B,N)
    float* __restrict__ out)          // (B,N)
{
    const int b    = blockIdx.x;
    const int tid  = threadIdx.x;
    const int hw   = tid >> 5;   // half-wave id 0..7
    const int lane = tid & 31;   // lane within half-wave
    const int e0   = lane * 4;

    __shared__ float xs[Nc];     // -(att * mask)  per n
    __shared__ float os[Nc];     // out_dist * mask per n
    __shared__ float red_s[8];   // cross-wave reduction scratch

    // Per-lane chunks of q, q_p, A1, A2 (each lane owns 4 consecutive e's).
    const float4 qv  = *reinterpret_cast<const float4*>(q   + (size_t)b * Ec + e0);
    const float4 qpv = *reinterpret_cast<const float4*>(q_p + (size_t)b * Ec + e0);
    const float4 a1v = *reinterpret_cast<const float4*>(A1  + e0);
    const float4 a2v = *reinterpret_cast<const float4*>(A2  + e0);

    const float* mb  = m   + (size_t)b * Nc * Ec;
    const float* mcb = m_c + (size_t)b * Nc * Ec;

    for (int pass = 0; pass < Nc / 8; ++pass) {
        const int n = pass * 8 + hw;
        const float4 mv  = *reinterpret_cast<const float4*>(mb  + (size_t)n * Ec + e0);
        const float4 mcv = *reinterpret_cast<const float4*>(mcb + (size_t)n * Ec + e0);

        float s_att = 0.f;  // sum over e of ((q-m)*A1)^2 + ((q_p-m)*A2)^2
        float s_out = 0.f;  // same with m_c

#define COMP(c) {                                               \
        float t1 = (qv.c  - mv.c)  * a1v.c;  s_att = fmaf(t1, t1, s_att); \
        float t2 = (qpv.c - mv.c)  * a2v.c;  s_att = fmaf(t2, t2, s_att); \
        float u1 = (qv.c  - mcv.c) * a1v.c;  s_out = fmaf(u1, u1, s_out); \
        float u2 = (qpv.c - mcv.c) * a2v.c;  s_out = fmaf(u2, u2, s_out); }
        COMP(x) COMP(y) COMP(z) COMP(w)
#undef COMP

        // Reduce across the 32-lane half-wave (xor masks <=16 keep lanes
        // within their own half of the wave64).
        for (int off = 16; off > 0; off >>= 1) {
            s_att += __shfl_xor(s_att, off);
            s_out += __shfl_xor(s_out, off);
        }

        if (lane == 0) {
            const float bb = biases[(size_t)b * Nc + n];
            const float mk = mask[(size_t)b * Nc + n];
            // att_dist = d1 + bias + d2 + bias = s_att + 2*bias
            xs[n] = -(s_att + 2.f * bb) * mk;   // softmax argument
            os[n] = (s_out + 2.f * bb) * mk;    // out_dist * mask
        }
    }
    __syncthreads();

    // Block-wide softmax over the 200 entries. Thread tid owns n = tid.
    float x = (tid < Nc) ? xs[tid] : -INFINITY;

    // max
    float wmax = x;
    for (int off = 32; off > 0; off >>= 1)
        wmax = fmaxf(wmax, __shfl_xor(wmax, off));
    if ((tid & 63) == 0) red_s[tid >> 6] = wmax;
    __syncthreads();
    const float gmax = fmaxf(fmaxf(red_s[0], red_s[1]), fmaxf(red_s[2], red_s[3]));

    // sum of exp
    const float ex = (tid < Nc) ? expf(x - gmax) : 0.f;
    float wsum = ex;
    for (int off = 32; off > 0; off >>= 1)
        wsum += __shfl_xor(wsum, off);
    if ((tid & 63) == 0) red_s[4 + (tid >> 6)] = wsum;
    __syncthreads();
    const float gsum = (red_s[4] + red_s[5]) + (red_s[6] + red_s[7]);

    if (tid < Nc) {
        out[(size_t)b * Nc + tid] = os[tid] * (ex / gsum);
    }
}

extern "C" void kernel_launch(void* const* d_in, const int* in_sizes, int n_in,
                              void* d_out, int out_size, void* d_ws, size_t ws_size,
                              hipStream_t stream) {
    const float* q      = (const float*)d_in[0];
    const float* q_p    = (const float*)d_in[1];
    const float* m      = (const float*)d_in[2];
    const float* m_c    = (const float*)d_in[3];
    const float* A1     = (const float*)d_in[4];
    const float* A2     = (const float*)d_in[5];
    const float* biases = (const float*)d_in[6];
    const float* mask   = (const float*)d_in[7];
    float* out = (float*)d_out;

    fused_dist_softmax<<<Bc, 256, 0, stream>>>(q, q_p, m, m_c, A1, A2, biases, mask, out);
}

// Round 2
// 242.012 us; speedup vs baseline: 1.0180x; 1.0180x over previous
//
#include <hip/hip_runtime.h>
#include <math.h>

// Problem constants (from reference setup_inputs): B=1024, N=200, E=128, fp32.
constexpr int Bc = 1024;
constexpr int Nc = 200;
constexpr int Ec = 128;
constexpr int ROWS = 5;     // rows per 32-lane group per pass
constexpr int PASSES = 5;   // Nc / (8 groups * ROWS) = 200/40

// One block per batch b. 256 threads = 8 groups of 32 lanes.
// Each group processes ROWS rows per pass: 32 lanes x float4 = 128 elems/row.
// ILP: 10 independent float4 loads in flight per lane, 10 interleaved
// shuffle-reduce chains -> hides HBM + ds-pipe latency (R1 was latency-bound:
// 15% HBM, 12% VALU).
__global__ __launch_bounds__(256) void fused_dist_softmax(
    const float* __restrict__ q,      // (B,E)
    const float* __restrict__ q_p,    // (B,E)
    const float* __restrict__ m,      // (B,N,E)
    const float* __restrict__ m_c,    // (B,N,E)
    const float* __restrict__ A1,     // (E,1) -> flat E
    const float* __restrict__ A2,     // (E,1) -> flat E
    const float* __restrict__ biases, // (B,N)
    const float* __restrict__ mask,   // (B,N)
    float* __restrict__ out)          // (B,N)
{
    const int b    = blockIdx.x;
    const int tid  = threadIdx.x;
    const int hw   = tid >> 5;   // group id 0..7
    const int lane = tid & 31;   // lane within group
    const int e0   = lane * 4;

    __shared__ float xs[Nc];     // -(att * mask)  per n
    __shared__ float os[Nc];     // out_dist * mask per n
    __shared__ float red_s[8];   // cross-wave reduction scratch

    // Per-lane chunks of q, q_p, A1, A2 (each lane owns 4 consecutive e's).
    const float4 qv  = *reinterpret_cast<const float4*>(q   + (size_t)b * Ec + e0);
    const float4 qpv = *reinterpret_cast<const float4*>(q_p + (size_t)b * Ec + e0);
    const float4 a1v = *reinterpret_cast<const float4*>(A1  + e0);
    const float4 a2v = *reinterpret_cast<const float4*>(A2  + e0);

    const float* mb  = m   + (size_t)b * Nc * Ec;
    const float* mcb = m_c + (size_t)b * Nc * Ec;

    for (int pass = 0; pass < PASSES; ++pass) {
        const int n0 = pass * (8 * ROWS) + hw * ROWS;

        // Issue all 10 loads first: max outstanding vmcnt per lane.
        float4 mv[ROWS], mcv[ROWS];
#pragma unroll
        for (int r = 0; r < ROWS; ++r) {
            mv[r]  = *reinterpret_cast<const float4*>(mb  + (size_t)(n0 + r) * Ec + e0);
            mcv[r] = *reinterpret_cast<const float4*>(mcb + (size_t)(n0 + r) * Ec + e0);
        }

        float s_att[ROWS], s_out[ROWS];
#pragma unroll
        for (int r = 0; r < ROWS; ++r) {
            float sa = 0.f, so = 0.f;
#define COMP(c) {                                                        \
            float t1 = (qv.c  - mv[r].c)  * a1v.c;  sa = fmaf(t1, t1, sa); \
            float t2 = (qpv.c - mv[r].c)  * a2v.c;  sa = fmaf(t2, t2, sa); \
            float u1 = (qv.c  - mcv[r].c) * a1v.c;  so = fmaf(u1, u1, so); \
            float u2 = (qpv.c - mcv[r].c) * a2v.c;  so = fmaf(u2, u2, so); }
            COMP(x) COMP(y) COMP(z) COMP(w)
#undef COMP
            s_att[r] = sa;
            s_out[r] = so;
        }

        // 10 interleaved shuffle-reduce chains (xor masks <=16 stay within
        // each 32-lane half of the wave64).
#pragma unroll
        for (int off = 16; off > 0; off >>= 1) {
#pragma unroll
            for (int r = 0; r < ROWS; ++r) {
                s_att[r] += __shfl_xor(s_att[r], off);
                s_out[r] += __shfl_xor(s_out[r], off);
            }
        }

        if (lane == 0) {
#pragma unroll
            for (int r = 0; r < ROWS; ++r) {
                const int n = n0 + r;
                const float bb = biases[(size_t)b * Nc + n];
                const float mk = mask[(size_t)b * Nc + n];
                // att_dist = d1 + bias + d2 + bias = s_att + 2*bias
                xs[n] = -(s_att[r] + 2.f * bb) * mk;   // softmax argument
                os[n] = (s_out[r] + 2.f * bb) * mk;    // out_dist * mask
            }
        }
    }
    __syncthreads();

    // Block-wide softmax over the 200 entries. Thread tid owns n = tid.
    float x = (tid < Nc) ? xs[tid] : -INFINITY;

    // max
    float wmax = x;
    for (int off = 32; off > 0; off >>= 1)
        wmax = fmaxf(wmax, __shfl_xor(wmax, off));
    if ((tid & 63) == 0) red_s[tid >> 6] = wmax;
    __syncthreads();
    const float gmax = fmaxf(fmaxf(red_s[0], red_s[1]), fmaxf(red_s[2], red_s[3]));

    // sum of exp
    const float ex = (tid < Nc) ? expf(x - gmax) : 0.f;
    float wsum = ex;
    for (int off = 32; off > 0; off >>= 1)
        wsum += __shfl_xor(wsum, off);
    if ((tid & 63) == 0) red_s[4 + (tid >> 6)] = wsum;
    __syncthreads();
    const float gsum = (red_s[4] + red_s[5]) + (red_s[6] + red_s[7]);

    if (tid < Nc) {
        out[(size_t)b * Nc + tid] = os[tid] * (ex / gsum);
    }
}

extern "C" void kernel_launch(void* const* d_in, const int* in_sizes, int n_in,
                              void* d_out, int out_size, void* d_ws, size_t ws_size,
                              hipStream_t stream) {
    const float* q      = (const float*)d_in[0];
    const float* q_p    = (const float*)d_in[1];
    const float* m      = (const float*)d_in[2];
    const float* m_c    = (const float*)d_in[3];
    const float* A1     = (const float*)d_in[4];
    const float* A2     = (const float*)d_in[5];
    const float* biases = (const float*)d_in[6];
    const float* mask   = (const float*)d_in[7];
    float* out = (float*)d_out;

    fused_dist_softmax<<<Bc, 256, 0, stream>>>(q, q_p, m, m_c, A1, A2, biases, mask, out);
}